// Round 2
// baseline (4020.082 us; speedup 1.0000x reference)
//
#include <hip/hip_runtime.h>
#include <hip/hip_bf16.h>
#include <cstddef>

#define IN_DIM 43
#define HID    64
#define H2     128   // 2*HID
#define NOUT   256   // 4*HID outputs per step
#define NCLS   5
#define BB     256
#define SS     4096
#define CH     32    // steps per feat chunk staged in LDS

__device__ __forceinline__ float fexp2(float x) { return __builtin_amdgcn_exp2f(x); }
__device__ __forceinline__ float frcp(float x)  { return __builtin_amdgcn_rcpf(x); }
// sigmoid(x) = 1/(1+e^-x); e^-x = 2^(-x*log2e). Saturates cleanly at +-inf.
__device__ __forceinline__ float sigmoid_f(float x) {
    return frcp(1.0f + fexp2(-1.44269504f * x));
}
// tanh(x) = sign(x) * (1-e^(-2|x|)) / (1+e^(-2|x|)); no overflow path.
__device__ __forceinline__ float tanh_f(float x) {
    float a = fabsf(x);
    float e = fexp2(-2.88539008f * a);
    float r = (1.0f - e) * frcp(1.0f + e);
    return copysignf(r, x);
}

// ---------------- Phase 1: x -> LN -> proj -> LN -> SiLU -> feat ----------------
__global__ __launch_bounds__(256) void feat_kernel(
    const float* __restrict__ x, const float* __restrict__ g_in, const float* __restrict__ b_in,
    const float* __restrict__ Wp, const float* __restrict__ bp,
    const float* __restrict__ g_p, const float* __restrict__ b_p,
    float* __restrict__ feat)
{
    __shared__ float sW[IN_DIM * HID];
    __shared__ float sgin[IN_DIM], sbin[IN_DIM];
    __shared__ float sbp[HID], sgp[HID], sbpp[HID];
    const int t = threadIdx.x;
    for (int i = t; i < IN_DIM * HID; i += 256) sW[i] = Wp[i];
    if (t < IN_DIM) { sgin[t] = g_in[t]; sbin[t] = b_in[t]; }
    if (t < HID)    { sbp[t] = bp[t]; sgp[t] = g_p[t]; sbpp[t] = b_p[t]; }
    __syncthreads();

    const size_t tok = (size_t)blockIdx.x * 256 + t;   // exactly B*S tokens
    const float* xp = x + tok * IN_DIM;

    float xv[IN_DIM];
    float s = 0.f;
    #pragma unroll
    for (int k = 0; k < IN_DIM; ++k) { xv[k] = xp[k]; s += xv[k]; }
    const float mu = s * (1.0f / IN_DIM);
    float v = 0.f;
    #pragma unroll
    for (int k = 0; k < IN_DIM; ++k) { float d = xv[k] - mu; v += d * d; }
    const float rs = rsqrtf(v * (1.0f / IN_DIM) + 1e-5f);
    #pragma unroll
    for (int k = 0; k < IN_DIM; ++k) xv[k] = (xv[k] - mu) * rs * sgin[k] + sbin[k];

    float acc[HID];
    #pragma unroll
    for (int j = 0; j < HID; ++j) acc[j] = sbp[j];
    for (int k = 0; k < IN_DIM; ++k) {          // rolled over k; inner unrolled
        const float xk = xv[k];
        #pragma unroll
        for (int j = 0; j < HID; ++j) acc[j] += xk * sW[k * HID + j];
    }

    float s2 = 0.f;
    #pragma unroll
    for (int j = 0; j < HID; ++j) s2 += acc[j];
    const float mu2 = s2 * (1.0f / HID);
    float v2 = 0.f;
    #pragma unroll
    for (int j = 0; j < HID; ++j) { float d = acc[j] - mu2; v2 += d * d; }
    const float rs2 = rsqrtf(v2 * (1.0f / HID) + 1e-5f);
    #pragma unroll
    for (int j = 0; j < HID; ++j) {
        float xh = (acc[j] - mu2) * rs2 * sgp[j] + sbpp[j];
        acc[j] = xh * sigmoid_f(xh);            // SiLU
    }
    float4* fo4 = (float4*)(feat + tok * HID);
    #pragma unroll
    for (int j = 0; j < HID / 4; ++j)
        fo4[j] = make_float4(acc[4*j], acc[4*j+1], acc[4*j+2], acc[4*j+3]);
}

// ---------------- Phase 2: the sequential scan, one batch row per block ----------------
// thread t: matrix g = t>>6 (ff1,ff2,ta,tb), column col = t&63.
// W column (128 floats) lives in VGPRs; z broadcast from LDS; feat streamed in
// 32-step chunks, double-buffered, register-prefetched one chunk ahead.
// seq output aliases the feat buffer (safe: feat[chunk c] is loaded during chunk
// c-1, overwritten during chunk c).
#define DOT4(acc, wb, zp) acc += w[(wb)+0]*zp.x + w[(wb)+1]*zp.y + w[(wb)+2]*zp.z + w[(wb)+3]*zp.w

__global__ __launch_bounds__(256, 1) void scan_kernel(
    const float* __restrict__ feat, const float* __restrict__ dt,
    const float* __restrict__ Wff1, const float* __restrict__ bff1,
    const float* __restrict__ Wff2, const float* __restrict__ bff2,
    const float* __restrict__ Wta,  const float* __restrict__ bta,
    const float* __restrict__ Wtb,  const float* __restrict__ btb,
    float* __restrict__ seq)
{
    const int t = threadIdx.x;
    const int b = blockIdx.x;
    const int g = t >> 6;          // wave-uniform
    const int col = t & 63;
    const float* Wsel = (g == 0) ? Wff1 : (g == 1) ? Wff2 : (g == 2) ? Wta : Wtb;
    const float* bsel = (g == 0) ? bff1 : (g == 1) ? bff2 : (g == 2) ? bta : btb;

    float w[H2];
    #pragma unroll
    for (int k = 0; k < H2; ++k) w[k] = Wsel[k * HID + col];
    const float bias = bsel[col];

    __shared__ __align__(16) float zx[2][CH][HID];   // feat chunks (double buffer)
    __shared__ float sdt[2][CH];
    __shared__ __align__(16) float hbuf[HID];
    __shared__ float obuf[NOUT];

    const float* featb = feat + (size_t)b * SS * HID;
    const float* dtb   = dt   + (size_t)b * SS;
    float* seqb        = seq  + (size_t)b * SS * HID;

    if (t < HID) hbuf[t] = 0.f;
    {   // preload chunk 0: 2048 floats = 512 float4, 2 per thread, coalesced
        const float4* src = (const float4*)featb;
        float4* dst = (float4*)&zx[0][0][0];
        dst[t]       = src[t];
        dst[t + 256] = src[t + 256];
        if (t < CH) sdt[0][t] = dtb[t];
    }
    __syncthreads();

    int cur = 0;
    for (int c = 0; c < SS / CH; ++c) {
        float4 q0, q1; float qdt = 0.f;
        const bool hn = (c + 1 < SS / CH);
        if (hn) {   // issue prefetch of next chunk now; consumed ~10K cycles later
            const float4* src = (const float4*)(featb + (size_t)(c + 1) * CH * HID);
            q0 = src[t];
            q1 = src[t + 256];
            if (t < CH) qdt = dtb[(c + 1) * CH + t];
        }
        for (int ss = 0; ss < CH; ++ss) {
            const float* zc = &zx[cur][ss][0];
            const float* hb = &hbuf[0];
            float a0 = bias, a1 = 0.f, a2 = 0.f, a3 = 0.f;
            #pragma unroll
            for (int k = 0; k < HID; k += 16) {   // x-part
                float4 z0 = *(const float4*)(zc + k);
                float4 z1 = *(const float4*)(zc + k + 4);
                float4 z2 = *(const float4*)(zc + k + 8);
                float4 z3 = *(const float4*)(zc + k + 12);
                DOT4(a0, k, z0); DOT4(a1, k + 4, z1);
                DOT4(a2, k + 8, z2); DOT4(a3, k + 12, z3);
            }
            #pragma unroll
            for (int k = 0; k < HID; k += 16) {   // h-part
                float4 z0 = *(const float4*)(hb + k);
                float4 z1 = *(const float4*)(hb + k + 4);
                float4 z2 = *(const float4*)(hb + k + 8);
                float4 z3 = *(const float4*)(hb + k + 12);
                DOT4(a0, HID + k, z0); DOT4(a1, HID + k + 4, z1);
                DOT4(a2, HID + k + 8, z2); DOT4(a3, HID + k + 12, z3);
            }
            obuf[t] = (a0 + a1) + (a2 + a3);
            __syncthreads();

            // activation phase: every wave computes all 64 h redundantly (no idle waves)
            const int l = t & 63;
            const float o0 = obuf[l];
            const float o1 = obuf[l + 64];
            const float o2 = obuf[l + 128];
            const float o3 = obuf[l + 192];
            const float dtt = sdt[cur][ss] * 10.0f;
            const float ti = sigmoid_f(o2 * dtt + o3);
            const float f1 = tanh_f(o0);
            const float f2 = tanh_f(o1);
            const float h = f1 + ti * (f2 - f1);
            if (t < HID) {
                hbuf[t] = h;
                seqb[(size_t)(c * CH + ss) * HID + t] = h;
            }
            __syncthreads();
        }
        if (hn) {   // commit prefetched chunk into the other LDS buffer
            float4* dst = (float4*)&zx[cur ^ 1][0][0];
            dst[t]       = q0;
            dst[t + 256] = q1;
            if (t < CH) sdt[cur ^ 1][t] = qdt;
            cur ^= 1;
            __syncthreads();
        }
    }
}

// ---------------- Phase 3: head, logits = seq @ W_head + b_head ----------------
__global__ __launch_bounds__(256) void head_kernel(
    const float* __restrict__ seq, const float* __restrict__ Wh,
    const float* __restrict__ bh, float* __restrict__ out)
{
    __shared__ float sW[HID * NCLS];
    __shared__ float sb[NCLS];
    const int t = threadIdx.x;
    for (int i = t; i < HID * NCLS; i += 256) sW[i] = Wh[i];
    if (t < NCLS) sb[t] = bh[t];
    __syncthreads();

    const size_t tok = (size_t)blockIdx.x * 256 + t;
    const float4* hp = (const float4*)(seq + tok * HID);
    float a[NCLS];
    #pragma unroll
    for (int c = 0; c < NCLS; ++c) a[c] = sb[c];
    #pragma unroll
    for (int k4 = 0; k4 < HID / 4; ++k4) {
        float4 hv = hp[k4];
        #pragma unroll
        for (int c = 0; c < NCLS; ++c) {
            a[c] += hv.x * sW[(4*k4+0)*NCLS + c] + hv.y * sW[(4*k4+1)*NCLS + c]
                  + hv.z * sW[(4*k4+2)*NCLS + c] + hv.w * sW[(4*k4+3)*NCLS + c];
        }
    }
    float* op = out + tok * NCLS;
    #pragma unroll
    for (int c = 0; c < NCLS; ++c) op[c] = a[c];
}

extern "C" void kernel_launch(void* const* d_in, const int* in_sizes, int n_in,
                              void* d_out, int out_size, void* d_ws, size_t ws_size,
                              hipStream_t stream)
{
    const float* x       = (const float*)d_in[0];
    const float* dt      = (const float*)d_in[1];
    const float* ln_in_g = (const float*)d_in[2];
    const float* ln_in_b = (const float*)d_in[3];
    const float* W_proj  = (const float*)d_in[4];
    const float* b_proj  = (const float*)d_in[5];
    const float* ln_p_g  = (const float*)d_in[6];
    const float* ln_p_b  = (const float*)d_in[7];
    const float* W_ff1   = (const float*)d_in[8];
    const float* b_ff1   = (const float*)d_in[9];
    const float* W_ff2   = (const float*)d_in[10];
    const float* b_ff2   = (const float*)d_in[11];
    const float* W_ta    = (const float*)d_in[12];
    const float* b_ta    = (const float*)d_in[13];
    const float* W_tb    = (const float*)d_in[14];
    const float* b_tb    = (const float*)d_in[15];
    const float* W_head  = (const float*)d_in[16];
    const float* b_head  = (const float*)d_in[17];
    float* out  = (float*)d_out;
    float* feat = (float*)d_ws;   // B*S*HID floats = 256 MiB; seq aliases it

    feat_kernel<<<dim3((BB * SS) / 256), dim3(256), 0, stream>>>(
        x, ln_in_g, ln_in_b, W_proj, b_proj, ln_p_g, ln_p_b, feat);
    scan_kernel<<<dim3(BB), dim3(256), 0, stream>>>(
        feat, dt, W_ff1, b_ff1, W_ff2, b_ff2, W_ta, b_ta, W_tb, b_tb, feat);
    head_kernel<<<dim3((BB * SS) / 256), dim3(256), 0, stream>>>(
        feat, W_head, b_head, out);
}

// Round 3
// 3111.030 us; speedup vs baseline: 1.2922x; 1.2922x over previous
//
#include <hip/hip_runtime.h>
#include <hip/hip_bf16.h>
#include <cstddef>

#define IN_DIM 43
#define HID    64
#define H2     128
#define NCLS   5
#define BB     256
#define SS     4096
#define CH     32    // steps per feat chunk staged in LDS

__device__ __forceinline__ float fexp2(float x) { return __builtin_amdgcn_exp2f(x); }
__device__ __forceinline__ float frcp(float x)  { return __builtin_amdgcn_rcpf(x); }
__device__ __forceinline__ float sigmoid_f(float x) {
    return frcp(1.0f + fexp2(-1.44269504f * x));
}
__device__ __forceinline__ float tanh_f(float x) {
    float a = fabsf(x);
    float e = fexp2(-2.88539008f * a);
    float r = (1.0f - e) * frcp(1.0f + e);
    return copysignf(r, x);
}

// ---------------- Phase 1: x -> LN -> proj -> LN -> SiLU -> feat (unchanged) ----------------
__global__ __launch_bounds__(256) void feat_kernel(
    const float* __restrict__ x, const float* __restrict__ g_in, const float* __restrict__ b_in,
    const float* __restrict__ Wp, const float* __restrict__ bp,
    const float* __restrict__ g_p, const float* __restrict__ b_p,
    float* __restrict__ feat)
{
    __shared__ float sW[IN_DIM * HID];
    __shared__ float sgin[IN_DIM], sbin[IN_DIM];
    __shared__ float sbp[HID], sgp[HID], sbpp[HID];
    const int t = threadIdx.x;
    for (int i = t; i < IN_DIM * HID; i += 256) sW[i] = Wp[i];
    if (t < IN_DIM) { sgin[t] = g_in[t]; sbin[t] = b_in[t]; }
    if (t < HID)    { sbp[t] = bp[t]; sgp[t] = g_p[t]; sbpp[t] = b_p[t]; }
    __syncthreads();

    const size_t tok = (size_t)blockIdx.x * 256 + t;
    const float* xp = x + tok * IN_DIM;

    float xv[IN_DIM];
    float s = 0.f;
    #pragma unroll
    for (int k = 0; k < IN_DIM; ++k) { xv[k] = xp[k]; s += xv[k]; }
    const float mu = s * (1.0f / IN_DIM);
    float v = 0.f;
    #pragma unroll
    for (int k = 0; k < IN_DIM; ++k) { float d = xv[k] - mu; v += d * d; }
    const float rs = rsqrtf(v * (1.0f / IN_DIM) + 1e-5f);
    #pragma unroll
    for (int k = 0; k < IN_DIM; ++k) xv[k] = (xv[k] - mu) * rs * sgin[k] + sbin[k];

    float acc[HID];
    #pragma unroll
    for (int j = 0; j < HID; ++j) acc[j] = sbp[j];
    for (int k = 0; k < IN_DIM; ++k) {
        const float xk = xv[k];
        #pragma unroll
        for (int j = 0; j < HID; ++j) acc[j] += xk * sW[k * HID + j];
    }

    float s2 = 0.f;
    #pragma unroll
    for (int j = 0; j < HID; ++j) s2 += acc[j];
    const float mu2 = s2 * (1.0f / HID);
    float v2 = 0.f;
    #pragma unroll
    for (int j = 0; j < HID; ++j) { float d = acc[j] - mu2; v2 += d * d; }
    const float rs2 = rsqrtf(v2 * (1.0f / HID) + 1e-5f);
    #pragma unroll
    for (int j = 0; j < HID; ++j) {
        float xh = (acc[j] - mu2) * rs2 * sgp[j] + sbpp[j];
        acc[j] = xh * sigmoid_f(xh);
    }
    float4* fo4 = (float4*)(feat + tok * HID);
    #pragma unroll
    for (int j = 0; j < HID / 4; ++j)
        fo4[j] = make_float4(acc[4*j], acc[4*j+1], acc[4*j+2], acc[4*j+3]);
}

// ---------------- Phase 2: scan. wave g = matrix, lane j = column. ----------------
// Weights in named float4 registers (guaranteed SROA). h lives in lane j of every
// wave; broadcast via v_readlane. One barrier/step; obuf parity double-buffered.
// Next step's x-part fills the o-exchange latency window.

#define REP16(M) M(0) M(1) M(2) M(3) M(4) M(5) M(6) M(7) M(8) M(9) M(10) M(11) M(12) M(13) M(14) M(15)

#define DW(i) float4 WX##i, WH##i;
#define LW(i) \
    WX##i = make_float4(Wsel[(4*(i)+0)*HID+col], Wsel[(4*(i)+1)*HID+col], \
                        Wsel[(4*(i)+2)*HID+col], Wsel[(4*(i)+3)*HID+col]); \
    WH##i = make_float4(Wsel[(64+4*(i)+0)*HID+col], Wsel[(64+4*(i)+1)*HID+col], \
                        Wsel[(64+4*(i)+2)*HID+col], Wsel[(64+4*(i)+3)*HID+col]);

// x-part: feat values are wave-uniform LDS broadcasts
#define XF(i) { float4 f = zf4[(i)]; \
    xb0 = fmaf(f.x, WX##i.x, xb0); xb1 = fmaf(f.y, WX##i.y, xb1); \
    xb2 = fmaf(f.z, WX##i.z, xb2); xb3 = fmaf(f.w, WX##i.w, xb3); }
#define XPART(ZP) { const float4* zf4 = (ZP); xb0 = bias; xb1 = 0.f; xb2 = 0.f; xb3 = 0.f; REP16(XF) }

// h-part: broadcast lane k's h via readlane (VALU, no LDS)
#define RLF(k) __int_as_float(__builtin_amdgcn_readlane(hvi, (k)))
#define HF(i) { \
    float h0 = RLF(4*(i)+0); xb0 = fmaf(h0, WH##i.x, xb0); \
    float h1 = RLF(4*(i)+1); xb1 = fmaf(h1, WH##i.y, xb1); \
    float h2 = RLF(4*(i)+2); xb2 = fmaf(h2, WH##i.z, xb2); \
    float h3 = RLF(4*(i)+3); xb3 = fmaf(h3, WH##i.w, xb3); }

__global__ __launch_bounds__(256, 1) void scan_kernel(
    const float* __restrict__ feat, const float* __restrict__ dt,
    const float* __restrict__ Wff1, const float* __restrict__ bff1,
    const float* __restrict__ Wff2, const float* __restrict__ bff2,
    const float* __restrict__ Wta,  const float* __restrict__ bta,
    const float* __restrict__ Wtb,  const float* __restrict__ btb,
    float* __restrict__ seq)
{
    const int t = threadIdx.x;
    const int b = blockIdx.x;
    const int g = t >> 6;          // wave-uniform matrix id
    const int col = t & 63;        // output column j
    const int j = col;
    const float* Wsel = (g == 0) ? Wff1 : (g == 1) ? Wff2 : (g == 2) ? Wta : Wtb;
    const float* bsel = (g == 0) ? bff1 : (g == 1) ? bff2 : (g == 2) ? bta : btb;
    const float bias = bsel[col];

    REP16(DW)
    REP16(LW)

    __shared__ __align__(16) float4 zx4[2][CH * 16];   // [2][CH][64 floats]
    __shared__ float sdt[2][CH];
    __shared__ float obuf[2][64][5];                   // pad 5: 2-way banks (free)

    const float* featb = feat + (size_t)b * SS * HID;
    const float* dtb   = dt   + (size_t)b * SS;
    float* seqb        = seq  + (size_t)b * SS * HID;

    // zero obuf (only slots 0,1 strictly needed for the h[-1]=0 trick; zero all 4)
    obuf[0][j][g] = 0.f; obuf[1][j][g] = 0.f;
    {   // preload chunk 0
        const float4* src = (const float4*)featb;
        zx4[0][t]       = src[t];
        zx4[0][t + 256] = src[t + 256];
        if (t < CH) sdt[0][t] = dtb[t];
    }
    __syncthreads();

    float xb0, xb1, xb2, xb3;
    float hv = 0.f;
    float dtprev = 0.f, dtnext = sdt[0][0];
    // "o[-1]" reads: zeros -> tanh(0)=0 -> h stays 0 on iteration (0,0)
    float op0 = obuf[1][j][0], op1 = obuf[1][j][1], op2 = obuf[1][j][2], op3 = obuf[1][j][3];
    XPART(&zx4[0][0])          // x-part for step 0

    int cur = 0;
    for (int c = 0; c < SS / CH; ++c) {
        float4 q0, q1; float qdt = 0.f;
        const bool hn = (c + 1 < SS / CH);
        if (hn) {   // prefetch next chunk into registers (consumed ~15K cycles later)
            const float4* src = (const float4*)(featb + (size_t)(c + 1) * CH * HID);
            q0 = src[t];
            q1 = src[t + 256];
            if (t < CH) qdt = dtb[(c + 1) * CH + t];
        }
        for (int ss = 0; ss < CH; ++ss) {
            const int ps = ss & 1;
            // A: finish step s-1: activation from previously-read o's (all waves, redundant)
            {
                const float dtt = dtprev * 10.0f;
                const float ti = sigmoid_f(fmaf(op2, dtt, op3));
                const float f1 = tanh_f(op0);
                const float f2 = tanh_f(op1);
                hv = fmaf(ti, f2 - f1, f1);
                if (g == 0 && (c | ss)) seqb[(size_t)(c * CH + ss - 1) * HID + j] = hv;
            }
            // B: h-part for step s accumulates onto the premade x-acc
            {
                const int hvi = __float_as_int(hv);
                REP16(HF)
            }
            // C: publish o
            obuf[ps][j][g] = (xb0 + xb1) + (xb2 + xb3);
            dtprev = dtnext;
            // D: the single per-step barrier
            __syncthreads();
            // E: issue o reads (consumed at next iteration's A)
            op0 = obuf[ps][j][0]; op1 = obuf[ps][j][1];
            op2 = obuf[ps][j][2]; op3 = obuf[ps][j][3];
            // F: x-part for step s+1 fills the read-latency window
            if (ss < CH - 1) {
                dtnext = sdt[cur][ss + 1];
                XPART(&zx4[cur][(ss + 1) * 16])
            }
        }
        if (hn) {   // commit prefetched chunk, then x-part for the new chunk's step 0
            float4* dst = &zx4[cur ^ 1][0];
            dst[t]       = q0;
            dst[t + 256] = q1;
            if (t < CH) sdt[cur ^ 1][t] = qdt;
            __syncthreads();
            cur ^= 1;
            dtnext = sdt[cur][0];
            XPART(&zx4[cur][0])
        }
    }
    // epilogue: finish step SS-1
    {
        const float dtt = dtprev * 10.0f;
        const float ti = sigmoid_f(fmaf(op2, dtt, op3));
        const float f1 = tanh_f(op0);
        const float f2 = tanh_f(op1);
        hv = fmaf(ti, f2 - f1, f1);
        if (g == 0) seqb[(size_t)(SS - 1) * HID + j] = hv;
    }
}

// ---------------- Phase 3: head (unchanged) ----------------
__global__ __launch_bounds__(256) void head_kernel(
    const float* __restrict__ seq, const float* __restrict__ Wh,
    const float* __restrict__ bh, float* __restrict__ out)
{
    __shared__ float sW[HID * NCLS];
    __shared__ float sb[NCLS];
    const int t = threadIdx.x;
    for (int i = t; i < HID * NCLS; i += 256) sW[i] = Wh[i];
    if (t < NCLS) sb[t] = bh[t];
    __syncthreads();

    const size_t tok = (size_t)blockIdx.x * 256 + t;
    const float4* hp = (const float4*)(seq + tok * HID);
    float a[NCLS];
    #pragma unroll
    for (int c = 0; c < NCLS; ++c) a[c] = sb[c];
    #pragma unroll
    for (int k4 = 0; k4 < HID / 4; ++k4) {
        float4 hv = hp[k4];
        #pragma unroll
        for (int c = 0; c < NCLS; ++c) {
            a[c] += hv.x * sW[(4*k4+0)*NCLS + c] + hv.y * sW[(4*k4+1)*NCLS + c]
                  + hv.z * sW[(4*k4+2)*NCLS + c] + hv.w * sW[(4*k4+3)*NCLS + c];
        }
    }
    float* op = out + tok * NCLS;
    #pragma unroll
    for (int c = 0; c < NCLS; ++c) op[c] = a[c];
}

extern "C" void kernel_launch(void* const* d_in, const int* in_sizes, int n_in,
                              void* d_out, int out_size, void* d_ws, size_t ws_size,
                              hipStream_t stream)
{
    const float* x       = (const float*)d_in[0];
    const float* dt      = (const float*)d_in[1];
    const float* ln_in_g = (const float*)d_in[2];
    const float* ln_in_b = (const float*)d_in[3];
    const float* W_proj  = (const float*)d_in[4];
    const float* b_proj  = (const float*)d_in[5];
    const float* ln_p_g  = (const float*)d_in[6];
    const float* ln_p_b  = (const float*)d_in[7];
    const float* W_ff1   = (const float*)d_in[8];
    const float* b_ff1   = (const float*)d_in[9];
    const float* W_ff2   = (const float*)d_in[10];
    const float* b_ff2   = (const float*)d_in[11];
    const float* W_ta    = (const float*)d_in[12];
    const float* b_ta    = (const float*)d_in[13];
    const float* W_tb    = (const float*)d_in[14];
    const float* b_tb    = (const float*)d_in[15];
    const float* W_head  = (const float*)d_in[16];
    const float* b_head  = (const float*)d_in[17];
    float* out  = (float*)d_out;
    float* feat = (float*)d_ws;   // B*S*HID floats = 256 MiB; seq aliases it

    feat_kernel<<<dim3((BB * SS) / 256), dim3(256), 0, stream>>>(
        x, ln_in_g, ln_in_b, W_proj, b_proj, ln_p_g, ln_p_b, feat);
    scan_kernel<<<dim3(BB), dim3(256), 0, stream>>>(
        feat, dt, W_ff1, b_ff1, W_ff2, b_ff2, W_ta, b_ta, W_tb, b_tb, feat);
    head_kernel<<<dim3((BB * SS) / 256), dim3(256), 0, stream>>>(
        feat, W_head, b_head, out);
}